// Round 21
// baseline (2037.298 us; speedup 1.0000x reference)
//
#include <hip/hip_runtime.h>

// TrajectoryDecoder: 2-layer LSTM (H=256), 45 steps, B=4096.
// R21: R20's two per-step kernels MERGED into one k_step with an 8-WG
// group barrier between layer0 and layer1 (dispatches 92 -> 48).
// Group = the 8 sl-WGs of a bt; mapping blockIdx = bt + 32*sl puts all
// members on one XCD (blockIdx % 8 == bt % 8). Barrier = R15's proven
// fence + monotonic-generation atomic pattern, zeroed per launch via
// hipMemsetAsync, bounded spin. Grid 256 @ 1 WG/CU = fully co-resident.
// All layouts / repack / head-fold / pos double-buffer identical to R20.
// mfma_f32_16x16x32_bf16: A row=lane&15(batch), k=(lane>>4)*8+j;
//   B col=lane&15(gate unit); C/D row=(lane>>4)*4+q, col=lane&15.

#define HN    256
#define DM    128
#define NSTEP 45

// ---- d_ws layout (bytes) ----
#define H0A_OFF  1605632ULL
#define HBUF_B   2097152ULL
#define H0B_OFF  (H0A_OFF + HBUF_B)
#define H1A_OFF  (H0B_OFF + HBUF_B)
#define H1B_OFF  (H1A_OFF + HBUF_B)
#define GX_OFF   (H1B_OFF + HBUF_B)
#define GX_B     8388608ULL
#define C0_OFF   (GX_OFF + GX_B)
#define CB_B     4194304ULL
#define C1_OFF   (C0_OFF + CB_B)
#define POSA_OFF (C1_OFF + CB_B)
#define POSB_OFF (POSA_OFF + 32768ULL)
#define GBAR_OFF (POSB_OFF + 32768ULL)     // 32 groups x 64B
#define WS_NEED  (GBAR_OFF + 2048ULL)

typedef __attribute__((ext_vector_type(8))) short s8v;
typedef __attribute__((ext_vector_type(4))) float f32x4;

#define MFMA16(a,b,c) __builtin_amdgcn_mfma_f32_16x16x32_bf16((a),(b),(c),0,0,0)

__device__ __forceinline__ unsigned short f2bf(float f){
  union { float f; unsigned u; } x; x.f = f;
  unsigned r = x.u + 0x7fffu + ((x.u >> 16) & 1u);
  return (unsigned short)(r >> 16);
}
__device__ __forceinline__ float bf2f(unsigned short h){
  union { unsigned u; float f; } x; x.u = ((unsigned)h) << 16;
  return x.f;
}
__device__ __forceinline__ float sigm(float x){
  x = fminf(40.f, fmaxf(-40.f, x));
  return 1.f/(1.f + __expf(-x));
}
__device__ __forceinline__ float tanhx(float x){
  float xx = fminf(15.f, fmaxf(-15.f, x));
  float e = __expf(2.f*xx);
  return (e-1.f)/(e+1.f);
}

// h tile layout (verified)
__device__ __forceinline__ void store_h(unsigned short* buf, int blk, int b, int u, float v){
  buf[(size_t)blk*4096 + (u>>5)*512 + ((b&15) + ((u>>3)&3)*16)*8 + (u&7)] = f2bf(v);
}
__device__ __forceinline__ s8v ld_af(const unsigned short* buf, int blk, int kt, int lane){
  return *(const s8v*)(buf + (size_t)blk*4096 + kt*512 + lane*8);
}

// 8-member group barrier (R15 pattern): gbar[0]=arrivals, gbar[1]=release gen
__device__ __forceinline__ void group_barrier(unsigned* gbar, unsigned gen){
  __syncthreads();
  if (threadIdx.x == 0){
    __threadfence();
    unsigned arrived = atomicAdd(gbar, 1u) + 1u;
    if (arrived == 8u*gen){
      __threadfence();
      atomicAdd(gbar+1, 1u);
    } else {
      unsigned spin = 0;
      while (atomicAdd(gbar+1, 0u) < gen && spin < (1u<<22)){
        __builtin_amdgcn_s_sleep(2); ++spin;
      }
    }
    __threadfence();
  }
  __syncthreads();
}

// ---- repack (unchanged, verified) ----
__global__ void repack(const float* __restrict__ Whh0, const float* __restrict__ Wih1,
                       const float* __restrict__ Whh1, const float* __restrict__ Wp1,
                       unsigned short* __restrict__ dst){
  int gid  = blockIdx.x*256 + threadIdx.x;
  int lane = gid & 63;
  int tile = gid >> 6;
  const float* src; int row; size_t doff;
  int k0 = (lane>>4)*8;
  if (tile < 1536){
    int mi = tile / 512;
    int r  = tile % 512;
    int ut = r & 15;
    int kt = (r >> 4) & 7;
    int g  = r >> 7;
    src  = (mi==0) ? Whh0 : (mi==1) ? Wih1 : Whh1;
    row  = g*256 + ut*16 + (lane&15);
    k0  += kt*32;
    doff = (size_t)mi*262144 + (size_t)r*512 + lane*8;
  } else {
    int r2 = tile - 1536;
    int kt = r2 & 7, pt = r2 >> 3;
    src  = Wp1;
    row  = pt*16 + (lane&15);
    k0  += kt*32;
    doff = 786432 + (size_t)r2*512 + lane*8;
  }
  const float* s = src + (size_t)row*HN + k0;
  float4 a = *(const float4*)(s);
  float4 b = *(const float4*)(s+4);
  unsigned short* d = dst + doff;
  d[0]=f2bf(a.x); d[1]=f2bf(a.y); d[2]=f2bf(a.z); d[3]=f2bf(a.w);
  d[4]=f2bf(b.x); d[5]=f2bf(b.y); d[6]=f2bf(b.z); d[7]=f2bf(b.w);
}

// ===================== init: h/c/gctx/pos state (unchanged) =====================
__global__ __launch_bounds__(512, 1)
void k_init(const float* __restrict__ enc, const float* __restrict__ pos0,
            const float* __restrict__ ctx, const float* __restrict__ Wh,
            const float* __restrict__ bh,  const float* __restrict__ Wc,
            const float* __restrict__ bc,  const float* __restrict__ Wih0,
            const float* __restrict__ bih0,const float* __restrict__ bhh0,
            unsigned short* __restrict__ h0a, unsigned short* __restrict__ h1a,
            unsigned short* __restrict__ gxg,
            float* __restrict__ c0g, float* __restrict__ c1g,
            float* __restrict__ posg)
{
  __shared__ float sh_x[16*DM];
  const int tid = threadIdx.x;
  const int blk = blockIdx.x;
  const int gb0 = blk*16;

  {
    const float4* src = (const float4*)(enc + (size_t)gb0*DM);
    ((float4*)sh_x)[tid] = src[tid];
  }
  if (tid < 32) posg[(size_t)gb0*2 + tid] = pos0[(size_t)gb0*2 + tid];
  __syncthreads();

  {
    const int r = tid;
    float ah[16], ac[16];
    #pragma unroll
    for (int b=0;b<16;b++){ ah[b]=0.f; ac[b]=0.f; }
    const float4* whr = (const float4*)(Wh + (size_t)r*DM);
    const float4* wcr = (const float4*)(Wc + (size_t)r*DM);
    #pragma unroll 4
    for (int kk=0; kk<DM/4; kk++){
      float4 w0 = whr[kk], w1 = wcr[kk];
      #pragma unroll
      for (int b=0;b<16;b++){
        float4 x = *(const float4*)&sh_x[b*DM + kk*4];
        ah[b] += w0.x*x.x + w0.y*x.y + w0.z*x.z + w0.w*x.w;
        ac[b] += w1.x*x.x + w1.y*x.y + w1.z*x.z + w1.w*x.w;
      }
    }
    float bhv = bh[r], bcv = bc[r];
    if (r < HN){
      #pragma unroll
      for (int b=0;b<16;b++){
        store_h(h0a, blk, b, r, ah[b] + bhv);
        c0g[(size_t)blk*4096 + r*16 + b] = ac[b] + bcv;
      }
    } else {
      #pragma unroll
      for (int b=0;b<16;b++){
        store_h(h1a, blk, b, r-HN, ah[b] + bhv);
        c1g[(size_t)blk*4096 + (r-HN)*16 + b] = ac[b] + bcv;
      }
    }
  }
  __syncthreads();

  {
    const float4* src = (const float4*)(ctx + (size_t)gb0*DM);
    ((float4*)sh_x)[tid] = src[tid];
  }
  __syncthreads();

  {
    float a0[16], a1[16];
    #pragma unroll
    for (int b=0;b<16;b++){ a0[b]=0.f; a1[b]=0.f; }
    const float2* wr0 = (const float2*)(Wih0 + (size_t)tid*130 + 2);
    const float2* wr1 = (const float2*)(Wih0 + (size_t)(tid+512)*130 + 2);
    #pragma unroll 4
    for (int kk=0; kk<DM/2; kk++){
      float2 w0 = wr0[kk], w1 = wr1[kk];
      #pragma unroll
      for (int b=0;b<16;b++){
        float2 x = *(const float2*)&sh_x[b*DM + kk*2];
        a0[b] += w0.x*x.x + w0.y*x.y;
        a1[b] += w1.x*x.x + w1.y*x.y;
      }
    }
    float cb0 = bih0[tid]     + bhh0[tid];
    float cb1 = bih0[tid+512] + bhh0[tid+512];
    #pragma unroll
    for (int b=0;b<16;b++){
      gxg[(size_t)blk*16384 + (size_t)tid*16 + b]       = f2bf(a0[b] + cb0);
      gxg[(size_t)blk*16384 + (size_t)(tid+512)*16 + b] = f2bf(a1[b] + cb1);
    }
  }
}

// ===================== k_step: head(t-1)+layer0 | group-bar | layer1 =====================
// grid 256: bt = blockIdx&31, sl = blockIdx>>5 (group co-located on one XCD).
__global__ __launch_bounds__(512, 1)
void k_step(const unsigned short* __restrict__ wsW,
            const unsigned short* __restrict__ gxg,
            const unsigned short* __restrict__ h0rd,
            unsigned short* __restrict__ h0wr,
            const unsigned short* __restrict__ h1rd,   // == h1prev
            unsigned short* __restrict__ h1wr,
            float* __restrict__ c0g, float* __restrict__ c1g,
            const float* __restrict__ posRd,
            float* __restrict__ posWr,
            const float* __restrict__ Wih0,
            const float* __restrict__ bih1, const float* __restrict__ bhh1,
            const float* __restrict__ bp1,
            const float* __restrict__ Wp2,
            const float* __restrict__ bp2,
            unsigned* __restrict__ bars,
            float* __restrict__ out, int t)
{
  const int tid  = threadIdx.x;
  const int lane = tid & 63;
  const int w    = tid >> 6;
  const int wb   = w >> 1;
  const int wh   = w & 1;
  const int col  = lane & 15;
  const int hi   = lane >> 4;
  const int bt   = blockIdx.x & 31;
  const int sl   = blockIdx.x >> 5;

  const int blk0 = bt*8 + wb*2;
  const int ut   = sl*2 + wh;
  const int u    = ut*16 + col;
  unsigned* gbar = bars + bt*16;

  // ================= PHASE A: head(t-1) + layer0 =================
  f32x4 acc[2][4];
  #pragma unroll
  for (int m2=0;m2<2;m2++)
    #pragma unroll
    for (int g=0;g<4;g++)
      #pragma unroll
      for (int q=0;q<4;q++) acc[m2][g][q] = 0.f;

  float p0[2][4], p1[2][4];

  if (t > 0){
    float bpv[4], w2a[4], w2b[4];
    #pragma unroll
    for (int n=0;n<4;n++){
      bpv[n] = bp1[n*16 + col];
      w2a[n] = Wp2[n*16 + col];
      w2b[n] = Wp2[64 + n*16 + col];
    }
    f32x4 hp[2][4];
    #pragma unroll
    for (int m2=0;m2<2;m2++)
      #pragma unroll
      for (int n=0;n<4;n++)
        #pragma unroll
        for (int q=0;q<4;q++) hp[m2][n][q] = bpv[n];

    #pragma unroll
    for (int kt=0;kt<8;kt++){
      s8v a0 = ld_af(h0rd, blk0,   kt, lane);
      s8v a1 = ld_af(h0rd, blk0+1, kt, lane);
      s8v b0 = ld_af(h1rd, blk0,   kt, lane);
      s8v b1 = ld_af(h1rd, blk0+1, kt, lane);
      #pragma unroll
      for (int g=0;g<4;g++){
        const int r = (g*8 + kt)*16 + ut;
        s8v bf = *(const s8v*)(wsW + (size_t)r*512 + lane*8);
        acc[0][g] = MFMA16(a0, bf, acc[0][g]);
        acc[1][g] = MFMA16(a1, bf, acc[1][g]);
        s8v wf = *(const s8v*)(wsW + 786432 + (size_t)(g*8+kt)*512 + lane*8);
        hp[0][g] = MFMA16(b0, wf, hp[0][g]);
        hp[1][g] = MFMA16(b1, wf, hp[1][g]);
      }
    }

    const float bp20 = bp2[0], bp21 = bp2[1];
    #pragma unroll
    for (int m2=0;m2<2;m2++){
      const int blk = blk0 + m2;
      #pragma unroll
      for (int q=0;q<4;q++){
        float s0 = 0.f, s1 = 0.f;
        #pragma unroll
        for (int n=0;n<4;n++){
          float r = fmaxf(hp[m2][n][q], 0.f);
          s0 += r*w2a[n]; s1 += r*w2b[n];
        }
        #pragma unroll
        for (int off=1; off<16; off<<=1){
          s0 += __shfl_xor(s0, off, 64);
          s1 += __shfl_xor(s1, off, 64);
        }
        int b = blk*16 + hi*4 + q;
        float2 pp = *(const float2*)(posRd + (size_t)b*2);
        float np0 = pp.x + s0 + bp20;
        float np1 = pp.y + s1 + bp21;
        p0[m2][q] = np0; p1[m2][q] = np1;
        if (sl == 0 && wh == 0 && col == 0){
          posWr[(size_t)b*2]     = np0;
          posWr[(size_t)b*2 + 1] = np1;
          out[((size_t)b*NSTEP + (t-1))*2]     = np0;
          out[((size_t)b*NSTEP + (t-1))*2 + 1] = np1;
        }
      }
    }
  } else {
    #pragma unroll
    for (int kt=0;kt<8;kt++){
      s8v a0 = ld_af(h0rd, blk0,   kt, lane);
      s8v a1 = ld_af(h0rd, blk0+1, kt, lane);
      #pragma unroll
      for (int g=0;g<4;g++){
        const int r = (g*8 + kt)*16 + ut;
        s8v bf = *(const s8v*)(wsW + (size_t)r*512 + lane*8);
        acc[0][g] = MFMA16(a0, bf, acc[0][g]);
        acc[1][g] = MFMA16(a1, bf, acc[1][g]);
      }
    }
    #pragma unroll
    for (int m2=0;m2<2;m2++)
      #pragma unroll
      for (int q=0;q<4;q++){
        float2 pp = *(const float2*)(posRd + (size_t)((blk0+m2)*16 + hi*4 + q)*2);
        p0[m2][q] = pp.x; p1[m2][q] = pp.y;
      }
  }

  // ---- add gctx + pos@Wpos, then cell0, write h0new ----
  {
    float wpr[4][2];
    #pragma unroll
    for (int g=0;g<4;g++){
      int row = g*256 + u;
      wpr[g][0] = Wih0[(size_t)row*130 + 0];
      wpr[g][1] = Wih0[(size_t)row*130 + 1];
    }
    #pragma unroll
    for (int m2=0;m2<2;m2++){
      const int blk = blk0 + m2;
      float* cp = c0g + (size_t)blk*4096 + u*16 + hi*4;
      float4 cold = *(const float4*)cp;
      float4 cnew;
      #pragma unroll
      for (int q=0;q<4;q++){
        float gate[4];
        #pragma unroll
        for (int g=0;g<4;g++){
          const unsigned short* gp = gxg + (size_t)blk*16384 + (size_t)(g*256+u)*16 + hi*4;
          gate[g] = acc[m2][g][q] + bf2f(gp[q]) + p0[m2][q]*wpr[g][0] + p1[m2][q]*wpr[g][1];
        }
        float iv = sigm(gate[0]);
        float fv = sigm(gate[1]);
        float gv = tanhx(gate[2]);
        float ov = sigm(gate[3]);
        float cv = fv*((&cold.x)[q]) + iv*gv;
        (&cnew.x)[q] = cv;
        store_h(h0wr, blk, hi*4+q, u, ov*tanhx(cv));
      }
      *(float4*)cp = cnew;
    }
  }

  // ================= group barrier: h0new visible across the 8 sl-WGs ========
  group_barrier(gbar, (unsigned)(t+1));

  // ================= PHASE B: layer1 =================
  #pragma unroll
  for (int g=0;g<4;g++){
    int row = g*256 + u;
    float bv = bih1[row] + bhh1[row];
    #pragma unroll
    for (int q=0;q<4;q++){ acc[0][g][q] = bv; acc[1][g][q] = bv; }
  }

  #pragma unroll
  for (int kt=0;kt<8;kt++){
    s8v x0 = ld_af(h0wr, blk0,   kt, lane);
    s8v x1 = ld_af(h0wr, blk0+1, kt, lane);
    s8v y0 = ld_af(h1rd, blk0,   kt, lane);
    s8v y1 = ld_af(h1rd, blk0+1, kt, lane);
    #pragma unroll
    for (int g=0;g<4;g++){
      const int r = (g*8 + kt)*16 + ut;
      s8v b1v = *(const s8v*)(wsW + 262144 + (size_t)r*512 + lane*8);
      acc[0][g] = MFMA16(x0, b1v, acc[0][g]);
      acc[1][g] = MFMA16(x1, b1v, acc[1][g]);
      s8v b2v = *(const s8v*)(wsW + 524288 + (size_t)r*512 + lane*8);
      acc[0][g] = MFMA16(y0, b2v, acc[0][g]);
      acc[1][g] = MFMA16(y1, b2v, acc[1][g]);
    }
  }

  #pragma unroll
  for (int m2=0;m2<2;m2++){
    const int blk = blk0 + m2;
    float* cp = c1g + (size_t)blk*4096 + u*16 + hi*4;
    float4 cold = *(const float4*)cp;
    float4 cnew;
    #pragma unroll
    for (int q=0;q<4;q++){
      float iv = sigm(acc[m2][0][q]);
      float fv = sigm(acc[m2][1][q]);
      float gv = tanhx(acc[m2][2][q]);
      float ov = sigm(acc[m2][3][q]);
      float cv = fv*((&cold.x)[q]) + iv*gv;
      (&cnew.x)[q] = cv;
      store_h(h1wr, blk, hi*4+q, u, ov*tanhx(cv));
    }
    *(float4*)cp = cnew;
  }
}

// ===================== k_head: final step's out only (unchanged) =====================
__global__ __launch_bounds__(256, 2)
void k_head(const unsigned short* __restrict__ wsW,
            const unsigned short* __restrict__ h1n,
            const float* __restrict__ posRd,
            const float* __restrict__ bp1,
            const float* __restrict__ Wp2,
            const float* __restrict__ bp2,
            float* __restrict__ out, int t)
{
  const int tid  = threadIdx.x;
  const int lane = tid & 63;
  const int w    = tid >> 6;
  const int col  = lane & 15;
  const int hi   = lane >> 4;
  const int bt   = blockIdx.x;

  float bpv[4], w2a[4], w2b[4];
  #pragma unroll
  for (int n=0;n<4;n++){
    bpv[n] = bp1[n*16 + col];
    w2a[n] = Wp2[n*16 + col];
    w2b[n] = Wp2[64 + n*16 + col];
  }
  const float bp20 = bp2[0], bp21 = bp2[1];

  #pragma unroll
  for (int m2=0;m2<2;m2++){
    const int blk = bt*8 + w*2 + m2;
    f32x4 acc[4];
    #pragma unroll
    for (int n=0;n<4;n++)
      #pragma unroll
      for (int q=0;q<4;q++) acc[n][q] = bpv[n];
    #pragma unroll
    for (int kt=0;kt<8;kt++){
      s8v a = ld_af(h1n, blk, kt, lane);
      #pragma unroll
      for (int n=0;n<4;n++){
        s8v bf = *(const s8v*)(wsW + 786432 + (size_t)(n*8+kt)*512 + lane*8);
        acc[n] = MFMA16(a, bf, acc[n]);
      }
    }
    #pragma unroll
    for (int q=0;q<4;q++){
      float s0 = 0.f, s1 = 0.f;
      #pragma unroll
      for (int n=0;n<4;n++){
        float r = fmaxf(acc[n][q], 0.f);
        s0 += r*w2a[n]; s1 += r*w2b[n];
      }
      #pragma unroll
      for (int off=1; off<16; off<<=1){
        s0 += __shfl_xor(s0, off, 64);
        s1 += __shfl_xor(s1, off, 64);
      }
      if (col == 0){
        int b = blk*16 + hi*4 + q;
        out[((size_t)b*NSTEP + t)*2]     = posRd[(size_t)b*2]     + s0 + bp20;
        out[((size_t)b*NSTEP + t)*2 + 1] = posRd[(size_t)b*2 + 1] + s1 + bp21;
      }
    }
  }
}

extern "C" void kernel_launch(void* const* d_in, const int* in_sizes, int n_in,
                              void* d_out, int out_size, void* d_ws, size_t ws_size,
                              hipStream_t stream) {
  const float* enc  = (const float*)d_in[0];
  const float* pos0 = (const float*)d_in[1];
  const float* ctx  = (const float*)d_in[2];
  const float* Wh   = (const float*)d_in[3];
  const float* bh   = (const float*)d_in[4];
  const float* Wc   = (const float*)d_in[5];
  const float* bc   = (const float*)d_in[6];
  const float* Wih0 = (const float*)d_in[7];
  const float* Whh0 = (const float*)d_in[8];
  const float* bih0 = (const float*)d_in[9];
  const float* bhh0 = (const float*)d_in[10];
  const float* Wih1 = (const float*)d_in[11];
  const float* Whh1 = (const float*)d_in[12];
  const float* bih1 = (const float*)d_in[13];
  const float* bhh1 = (const float*)d_in[14];
  const float* Wp1  = (const float*)d_in[15];
  const float* bp1  = (const float*)d_in[16];
  const float* Wp2  = (const float*)d_in[17];
  const float* bp2  = (const float*)d_in[18];
  float* out = (float*)d_out;
  unsigned short* wsW = (unsigned short*)d_ws;

  unsigned short* h0a = (unsigned short*)((char*)d_ws + H0A_OFF);
  unsigned short* h0b = (unsigned short*)((char*)d_ws + H0B_OFF);
  unsigned short* h1a = (unsigned short*)((char*)d_ws + H1A_OFF);
  unsigned short* h1b = (unsigned short*)((char*)d_ws + H1B_OFF);
  unsigned short* gxg = (unsigned short*)((char*)d_ws + GX_OFF);
  float* c0g  = (float*)((char*)d_ws + C0_OFF);
  float* c1g  = (float*)((char*)d_ws + C1_OFF);
  float* posA = (float*)((char*)d_ws + POSA_OFF);
  float* posB = (float*)((char*)d_ws + POSB_OFF);
  unsigned* bars = (unsigned*)((char*)d_ws + GBAR_OFF);

  hipMemsetAsync((void*)bars, 0, 2048, stream);

  hipLaunchKernelGGL(repack, dim3(392), dim3(256), 0, stream,
                     Whh0, Wih1, Whh1, Wp1, wsW);

  hipLaunchKernelGGL(k_init, dim3(256), dim3(512), 0, stream,
                     enc, pos0, ctx, Wh, bh, Wc, bc, Wih0, bih0, bhh0,
                     h0a, h1a, gxg, c0g, c1g, posA);

  unsigned short* h1prev = h1a;
  for (int t = 0; t < NSTEP; t++){
    unsigned short* h0r = (t & 1) ? h0b : h0a;
    unsigned short* h0w = (t & 1) ? h0a : h0b;
    unsigned short* h1r = (t & 1) ? h1b : h1a;   // == h1prev
    unsigned short* h1w = (t & 1) ? h1a : h1b;
    float* posRead  = (t == 0) ? posA : ((t & 1) ? posA : posB);
    float* posWrite = (t & 1) ? posB : posA;

    hipLaunchKernelGGL(k_step, dim3(256), dim3(512), 0, stream,
                       wsW, gxg, h0r, h0w, h1r, h1w, c0g, c1g,
                       posRead, posWrite, Wih0, bih1, bhh1,
                       bp1, Wp2, bp2, bars, out, t);
    h1prev = h1w;
  }
  hipLaunchKernelGGL(k_head, dim3(32), dim3(256), 0, stream,
                     wsW, h1prev, posA, bp1, Wp2, bp2, out, NSTEP-1);
}

// Round 22
// 1843.632 us; speedup vs baseline: 1.1050x; 1.1050x over previous
//
#include <hip/hip_runtime.h>

// TrajectoryDecoder: 2-layer LSTM (H=256), 45 steps, B=4096.
// R22 = R19 restored (best measured: 1.839 ms). Multi-kernel GEMM tiling:
// per step k_layer0 (head(t-1) folded in) + k_layer1; grid 32 bt x 8 sl =
// 256 WGs x 512 thr (1 WG/CU, 8 waves), M=128 x N=128 per WG. Weights
// bf16-repacked B-frag tiles; h double-buffered in A-frag tile layout;
// gctx bf16; c0/c1 fp32; pos double-buffered. R20's interleave (null),
// R21's intra-kernel barrier (-11%) reverted per post-mortems.
// mfma_f32_16x16x32_bf16: A row=lane&15(batch), k=(lane>>4)*8+j;
//   B col=lane&15(gate unit); C/D row=(lane>>4)*4+q, col=lane&15.

#define HN    256
#define DM    128
#define NSTEP 45

// ---- d_ws layout (bytes) ----
#define H0A_OFF  1605632ULL
#define HBUF_B   2097152ULL                 // 4096*256*2 bytes
#define H0B_OFF  (H0A_OFF + HBUF_B)
#define H1A_OFF  (H0B_OFF + HBUF_B)
#define H1B_OFF  (H1A_OFF + HBUF_B)
#define GX_OFF   (H1B_OFF + HBUF_B)         // gctx bf16 [256 blk][1024 row][16 b]
#define GX_B     8388608ULL
#define C0_OFF   (GX_OFF + GX_B)            // c0 fp32 [256 blk][256 u][16 b]
#define CB_B     4194304ULL
#define C1_OFF   (C0_OFF + CB_B)
#define POSA_OFF (C1_OFF + CB_B)
#define POSB_OFF (POSA_OFF + 32768ULL)
#define WS_NEED  (POSB_OFF + 32768ULL)

typedef __attribute__((ext_vector_type(8))) short s8v;
typedef __attribute__((ext_vector_type(4))) float f32x4;

#define MFMA16(a,b,c) __builtin_amdgcn_mfma_f32_16x16x32_bf16((a),(b),(c),0,0,0)

__device__ __forceinline__ unsigned short f2bf(float f){
  union { float f; unsigned u; } x; x.f = f;
  unsigned r = x.u + 0x7fffu + ((x.u >> 16) & 1u);
  return (unsigned short)(r >> 16);
}
__device__ __forceinline__ float bf2f(unsigned short h){
  union { unsigned u; float f; } x; x.u = ((unsigned)h) << 16;
  return x.f;
}
__device__ __forceinline__ float sigm(float x){
  x = fminf(40.f, fmaxf(-40.f, x));
  return 1.f/(1.f + __expf(-x));
}
__device__ __forceinline__ float tanhx(float x){
  float xx = fminf(15.f, fmaxf(-15.f, x));
  float e = __expf(2.f*xx);
  return (e-1.f)/(e+1.f);
}

// h tile layout (verified): elem (blk, b, u) at
//   blk*4096 + (u>>5)*512 + ((b&15) + ((u>>3)&3)*16)*8 + (u&7)   [ushorts]
__device__ __forceinline__ void store_h(unsigned short* buf, int blk, int b, int u, float v){
  buf[(size_t)blk*4096 + (u>>5)*512 + ((b&15) + ((u>>3)&3)*16)*8 + (u&7)] = f2bf(v);
}
__device__ __forceinline__ s8v ld_af(const unsigned short* buf, int blk, int kt, int lane){
  return *(const s8v*)(buf + (size_t)blk*4096 + kt*512 + lane*8);
}

// ---- repack (unchanged, verified): fp32 -> bf16 B-frag tiles ----
__global__ void repack(const float* __restrict__ Whh0, const float* __restrict__ Wih1,
                       const float* __restrict__ Whh1, const float* __restrict__ Wp1,
                       unsigned short* __restrict__ dst){
  int gid  = blockIdx.x*256 + threadIdx.x;
  int lane = gid & 63;
  int tile = gid >> 6;
  const float* src; int row; size_t doff;
  int k0 = (lane>>4)*8;
  if (tile < 1536){
    int mi = tile / 512;
    int r  = tile % 512;
    int ut = r & 15;
    int kt = (r >> 4) & 7;
    int g  = r >> 7;
    src  = (mi==0) ? Whh0 : (mi==1) ? Wih1 : Whh1;
    row  = g*256 + ut*16 + (lane&15);
    k0  += kt*32;
    doff = (size_t)mi*262144 + (size_t)r*512 + lane*8;
  } else {
    int r2 = tile - 1536;
    int kt = r2 & 7, pt = r2 >> 3;
    src  = Wp1;
    row  = pt*16 + (lane&15);
    k0  += kt*32;
    doff = 786432 + (size_t)r2*512 + lane*8;
  }
  const float* s = src + (size_t)row*HN + k0;
  float4 a = *(const float4*)(s);
  float4 b = *(const float4*)(s+4);
  unsigned short* d = dst + doff;
  d[0]=f2bf(a.x); d[1]=f2bf(a.y); d[2]=f2bf(a.z); d[3]=f2bf(a.w);
  d[4]=f2bf(b.x); d[5]=f2bf(b.y); d[6]=f2bf(b.z); d[7]=f2bf(b.w);
}

// ===================== init: h/c/gctx/pos state =====================
__global__ __launch_bounds__(512, 1)
void k_init(const float* __restrict__ enc, const float* __restrict__ pos0,
            const float* __restrict__ ctx, const float* __restrict__ Wh,
            const float* __restrict__ bh,  const float* __restrict__ Wc,
            const float* __restrict__ bc,  const float* __restrict__ Wih0,
            const float* __restrict__ bih0,const float* __restrict__ bhh0,
            unsigned short* __restrict__ h0a, unsigned short* __restrict__ h1a,
            unsigned short* __restrict__ gxg,
            float* __restrict__ c0g, float* __restrict__ c1g,
            float* __restrict__ posg)
{
  __shared__ float sh_x[16*DM];
  const int tid = threadIdx.x;
  const int blk = blockIdx.x;
  const int gb0 = blk*16;

  {
    const float4* src = (const float4*)(enc + (size_t)gb0*DM);
    ((float4*)sh_x)[tid] = src[tid];
  }
  if (tid < 32) posg[(size_t)gb0*2 + tid] = pos0[(size_t)gb0*2 + tid];
  __syncthreads();

  {
    const int r = tid;
    float ah[16], ac[16];
    #pragma unroll
    for (int b=0;b<16;b++){ ah[b]=0.f; ac[b]=0.f; }
    const float4* whr = (const float4*)(Wh + (size_t)r*DM);
    const float4* wcr = (const float4*)(Wc + (size_t)r*DM);
    #pragma unroll 4
    for (int kk=0; kk<DM/4; kk++){
      float4 w0 = whr[kk], w1 = wcr[kk];
      #pragma unroll
      for (int b=0;b<16;b++){
        float4 x = *(const float4*)&sh_x[b*DM + kk*4];
        ah[b] += w0.x*x.x + w0.y*x.y + w0.z*x.z + w0.w*x.w;
        ac[b] += w1.x*x.x + w1.y*x.y + w1.z*x.z + w1.w*x.w;
      }
    }
    float bhv = bh[r], bcv = bc[r];
    if (r < HN){
      #pragma unroll
      for (int b=0;b<16;b++){
        store_h(h0a, blk, b, r, ah[b] + bhv);
        c0g[(size_t)blk*4096 + r*16 + b] = ac[b] + bcv;
      }
    } else {
      #pragma unroll
      for (int b=0;b<16;b++){
        store_h(h1a, blk, b, r-HN, ah[b] + bhv);
        c1g[(size_t)blk*4096 + (r-HN)*16 + b] = ac[b] + bcv;
      }
    }
  }
  __syncthreads();

  {
    const float4* src = (const float4*)(ctx + (size_t)gb0*DM);
    ((float4*)sh_x)[tid] = src[tid];
  }
  __syncthreads();

  {
    float a0[16], a1[16];
    #pragma unroll
    for (int b=0;b<16;b++){ a0[b]=0.f; a1[b]=0.f; }
    const float2* wr0 = (const float2*)(Wih0 + (size_t)tid*130 + 2);
    const float2* wr1 = (const float2*)(Wih0 + (size_t)(tid+512)*130 + 2);
    #pragma unroll 4
    for (int kk=0; kk<DM/2; kk++){
      float2 w0 = wr0[kk], w1 = wr1[kk];
      #pragma unroll
      for (int b=0;b<16;b++){
        float2 x = *(const float2*)&sh_x[b*DM + kk*2];
        a0[b] += w0.x*x.x + w0.y*x.y;
        a1[b] += w1.x*x.x + w1.y*x.y;
      }
    }
    float cb0 = bih0[tid]     + bhh0[tid];
    float cb1 = bih0[tid+512] + bhh0[tid+512];
    #pragma unroll
    for (int b=0;b<16;b++){
      gxg[(size_t)blk*16384 + (size_t)tid*16 + b]       = f2bf(a0[b] + cb0);
      gxg[(size_t)blk*16384 + (size_t)(tid+512)*16 + b] = f2bf(a1[b] + cb1);
    }
  }
}

// ===================== k1: head(t-1) + layer0 gates + cell =====================
// grid: bt(0..31)*8 + sl(0..7); TPB 512 (8 waves: w=(wb<<1)|wh).
__global__ __launch_bounds__(512, 1)
void k_layer0(const unsigned short* __restrict__ wsW,
              const unsigned short* __restrict__ gxg,
              const unsigned short* __restrict__ h0rd,
              unsigned short* __restrict__ h0wr,
              const unsigned short* __restrict__ h1prev,
              float* __restrict__ c0g,
              const float* __restrict__ posRd,
              float* __restrict__ posWr,
              const float* __restrict__ Wih0,
              const float* __restrict__ bp1,
              const float* __restrict__ Wp2,
              const float* __restrict__ bp2,
              float* __restrict__ out, int t)
{
  const int tid  = threadIdx.x;
  const int lane = tid & 63;
  const int w    = tid >> 6;       // 0..7
  const int wb   = w >> 1;         // 0..3 block-pair
  const int wh   = w & 1;          // 0..1 unit half
  const int col  = lane & 15;
  const int hi   = lane >> 4;
  const int bt   = blockIdx.x >> 3;
  const int sl   = blockIdx.x & 7;

  const int blk0 = bt*8 + wb*2;
  const int ut   = sl*2 + wh;      // unit-tile 0..15
  const int u    = ut*16 + col;    // owned unit

  // ---- pos for this wave's 2 blocks (fold head(t-1) when t>0) ----
  float p0[2][4], p1[2][4];
  if (t > 0){
    float bpv[4], w2a[4], w2b[4];
    #pragma unroll
    for (int n=0;n<4;n++){
      bpv[n] = bp1[n*16 + col];
      w2a[n] = Wp2[n*16 + col];
      w2b[n] = Wp2[64 + n*16 + col];
    }
    #pragma unroll
    for (int m2=0;m2<2;m2++){
      const int blk = blk0 + m2;
      f32x4 hp[4];
      #pragma unroll
      for (int n=0;n<4;n++)
        #pragma unroll
        for (int q=0;q<4;q++) hp[n][q] = bpv[n];
      #pragma unroll
      for (int kt=0;kt<8;kt++){
        s8v a = ld_af(h1prev, blk, kt, lane);
        #pragma unroll
        for (int n=0;n<4;n++){
          s8v bf = *(const s8v*)(wsW + 786432 + (size_t)(n*8+kt)*512 + lane*8);
          hp[n] = MFMA16(a, bf, hp[n]);
        }
      }
      #pragma unroll
      for (int q=0;q<4;q++){
        float s0 = 0.f, s1 = 0.f;
        #pragma unroll
        for (int n=0;n<4;n++){
          float r = fmaxf(hp[n][q], 0.f);
          s0 += r*w2a[n]; s1 += r*w2b[n];
        }
        #pragma unroll
        for (int off=1; off<16; off<<=1){
          s0 += __shfl_xor(s0, off, 64);
          s1 += __shfl_xor(s1, off, 64);
        }
        int b = blk*16 + hi*4 + q;
        float2 pp = *(const float2*)(posRd + (size_t)b*2);
        float np0 = pp.x + s0 + bp2[0];
        float np1 = pp.y + s1 + bp2[1];
        p0[m2][q] = np0; p1[m2][q] = np1;
        if (sl == 0 && wh == 0 && col == 0){
          posWr[(size_t)b*2]     = np0;
          posWr[(size_t)b*2 + 1] = np1;
          out[((size_t)b*NSTEP + (t-1))*2]     = np0;
          out[((size_t)b*NSTEP + (t-1))*2 + 1] = np1;
        }
      }
    }
  } else {
    #pragma unroll
    for (int m2=0;m2<2;m2++)
      #pragma unroll
      for (int q=0;q<4;q++){
        float2 pp = *(const float2*)(posRd + (size_t)((blk0+m2)*16 + hi*4 + q)*2);
        p0[m2][q] = pp.x; p1[m2][q] = pp.y;
      }
  }

  // ---- layer0 gates ----
  float wpr[4][2];
  #pragma unroll
  for (int g=0;g<4;g++){
    int row = g*256 + u;
    wpr[g][0] = Wih0[(size_t)row*130 + 0];
    wpr[g][1] = Wih0[(size_t)row*130 + 1];
  }

  f32x4 acc[2][4];
  #pragma unroll
  for (int m2=0;m2<2;m2++){
    const int blk = blk0 + m2;
    #pragma unroll
    for (int g=0;g<4;g++){
      int row = g*256 + u;
      const unsigned short* gp = gxg + (size_t)blk*16384 + (size_t)row*16 + hi*4;
      #pragma unroll
      for (int q=0;q<4;q++)
        acc[m2][g][q] = bf2f(gp[q]) + p0[m2][q]*wpr[g][0] + p1[m2][q]*wpr[g][1];
    }
  }

  #pragma unroll
  for (int kt=0;kt<8;kt++){
    s8v a0 = ld_af(h0rd, blk0,   kt, lane);
    s8v a1 = ld_af(h0rd, blk0+1, kt, lane);
    #pragma unroll
    for (int g=0;g<4;g++){
      const int r = (g*8 + kt)*16 + ut;
      s8v bf = *(const s8v*)(wsW + (size_t)r*512 + lane*8);
      acc[0][g] = MFMA16(a0, bf, acc[0][g]);
      acc[1][g] = MFMA16(a1, bf, acc[1][g]);
    }
  }

  // ---- cell0 ----
  #pragma unroll
  for (int m2=0;m2<2;m2++){
    const int blk = blk0 + m2;
    float* cp = c0g + (size_t)blk*4096 + u*16 + hi*4;
    float4 cold = *(const float4*)cp;
    float4 cnew;
    #pragma unroll
    for (int q=0;q<4;q++){
      float iv = sigm(acc[m2][0][q]);
      float fv = sigm(acc[m2][1][q]);
      float gv = tanhx(acc[m2][2][q]);
      float ov = sigm(acc[m2][3][q]);
      float cv = fv*((&cold.x)[q]) + iv*gv;
      (&cnew.x)[q] = cv;
      store_h(h0wr, blk, hi*4+q, u, ov*tanhx(cv));
    }
    *(float4*)cp = cnew;
  }
}

// ===================== k2: layer1 gates + cell =====================
__global__ __launch_bounds__(512, 1)
void k_layer1(const unsigned short* __restrict__ wsW,
              const unsigned short* __restrict__ h0n,
              const unsigned short* __restrict__ h1rd,
              unsigned short* __restrict__ h1wr,
              float* __restrict__ c1g,
              const float* __restrict__ bih1,
              const float* __restrict__ bhh1)
{
  const int tid  = threadIdx.x;
  const int lane = tid & 63;
  const int w    = tid >> 6;
  const int wb   = w >> 1;
  const int wh   = w & 1;
  const int col  = lane & 15;
  const int hi   = lane >> 4;
  const int bt   = blockIdx.x >> 3;
  const int sl   = blockIdx.x & 7;

  const int blk0 = bt*8 + wb*2;
  const int ut   = sl*2 + wh;
  const int u    = ut*16 + col;

  f32x4 acc[2][4];
  #pragma unroll
  for (int g=0;g<4;g++){
    int row = g*256 + u;
    float bv = bih1[row] + bhh1[row];
    #pragma unroll
    for (int q=0;q<4;q++){ acc[0][g][q] = bv; acc[1][g][q] = bv; }
  }

  #pragma unroll
  for (int kt=0;kt<8;kt++){
    s8v a0 = ld_af(h0n, blk0,   kt, lane);
    s8v a1 = ld_af(h0n, blk0+1, kt, lane);
    #pragma unroll
    for (int g=0;g<4;g++){
      const int r = (g*8 + kt)*16 + ut;
      s8v bf = *(const s8v*)(wsW + 262144 + (size_t)r*512 + lane*8);
      acc[0][g] = MFMA16(a0, bf, acc[0][g]);
      acc[1][g] = MFMA16(a1, bf, acc[1][g]);
    }
  }
  #pragma unroll
  for (int kt=0;kt<8;kt++){
    s8v a0 = ld_af(h1rd, blk0,   kt, lane);
    s8v a1 = ld_af(h1rd, blk0+1, kt, lane);
    #pragma unroll
    for (int g=0;g<4;g++){
      const int r = (g*8 + kt)*16 + ut;
      s8v bf = *(const s8v*)(wsW + 524288 + (size_t)r*512 + lane*8);
      acc[0][g] = MFMA16(a0, bf, acc[0][g]);
      acc[1][g] = MFMA16(a1, bf, acc[1][g]);
    }
  }

  #pragma unroll
  for (int m2=0;m2<2;m2++){
    const int blk = blk0 + m2;
    float* cp = c1g + (size_t)blk*4096 + u*16 + hi*4;
    float4 cold = *(const float4*)cp;
    float4 cnew;
    #pragma unroll
    for (int q=0;q<4;q++){
      float iv = sigm(acc[m2][0][q]);
      float fv = sigm(acc[m2][1][q]);
      float gv = tanhx(acc[m2][2][q]);
      float ov = sigm(acc[m2][3][q]);
      float cv = fv*((&cold.x)[q]) + iv*gv;
      (&cnew.x)[q] = cv;
      store_h(h1wr, blk, hi*4+q, u, ov*tanhx(cv));
    }
    *(float4*)cp = cnew;
  }
}

// ===================== k_head: final step's out only =====================
__global__ __launch_bounds__(256, 2)
void k_head(const unsigned short* __restrict__ wsW,
            const unsigned short* __restrict__ h1n,
            const float* __restrict__ posRd,
            const float* __restrict__ bp1,
            const float* __restrict__ Wp2,
            const float* __restrict__ bp2,
            float* __restrict__ out, int t)
{
  const int tid  = threadIdx.x;
  const int lane = tid & 63;
  const int w    = tid >> 6;
  const int col  = lane & 15;
  const int hi   = lane >> 4;
  const int bt   = blockIdx.x;

  float bpv[4], w2a[4], w2b[4];
  #pragma unroll
  for (int n=0;n<4;n++){
    bpv[n] = bp1[n*16 + col];
    w2a[n] = Wp2[n*16 + col];
    w2b[n] = Wp2[64 + n*16 + col];
  }
  const float bp20 = bp2[0], bp21 = bp2[1];

  #pragma unroll
  for (int m2=0;m2<2;m2++){
    const int blk = bt*8 + w*2 + m2;
    f32x4 acc[4];
    #pragma unroll
    for (int n=0;n<4;n++)
      #pragma unroll
      for (int q=0;q<4;q++) acc[n][q] = bpv[n];
    #pragma unroll
    for (int kt=0;kt<8;kt++){
      s8v a = ld_af(h1n, blk, kt, lane);
      #pragma unroll
      for (int n=0;n<4;n++){
        s8v bf = *(const s8v*)(wsW + 786432 + (size_t)(n*8+kt)*512 + lane*8);
        acc[n] = MFMA16(a, bf, acc[n]);
      }
    }
    #pragma unroll
    for (int q=0;q<4;q++){
      float s0 = 0.f, s1 = 0.f;
      #pragma unroll
      for (int n=0;n<4;n++){
        float r = fmaxf(acc[n][q], 0.f);
        s0 += r*w2a[n]; s1 += r*w2b[n];
      }
      #pragma unroll
      for (int off=1; off<16; off<<=1){
        s0 += __shfl_xor(s0, off, 64);
        s1 += __shfl_xor(s1, off, 64);
      }
      if (col == 0){
        int b = blk*16 + hi*4 + q;
        out[((size_t)b*NSTEP + t)*2]     = posRd[(size_t)b*2]     + s0 + bp20;
        out[((size_t)b*NSTEP + t)*2 + 1] = posRd[(size_t)b*2 + 1] + s1 + bp21;
      }
    }
  }
}

extern "C" void kernel_launch(void* const* d_in, const int* in_sizes, int n_in,
                              void* d_out, int out_size, void* d_ws, size_t ws_size,
                              hipStream_t stream) {
  const float* enc  = (const float*)d_in[0];
  const float* pos0 = (const float*)d_in[1];
  const float* ctx  = (const float*)d_in[2];
  const float* Wh   = (const float*)d_in[3];
  const float* bh   = (const float*)d_in[4];
  const float* Wc   = (const float*)d_in[5];
  const float* bc   = (const float*)d_in[6];
  const float* Wih0 = (const float*)d_in[7];
  const float* Whh0 = (const float*)d_in[8];
  const float* bih0 = (const float*)d_in[9];
  const float* bhh0 = (const float*)d_in[10];
  const float* Wih1 = (const float*)d_in[11];
  const float* Whh1 = (const float*)d_in[12];
  const float* bih1 = (const float*)d_in[13];
  const float* bhh1 = (const float*)d_in[14];
  const float* Wp1  = (const float*)d_in[15];
  const float* bp1  = (const float*)d_in[16];
  const float* Wp2  = (const float*)d_in[17];
  const float* bp2  = (const float*)d_in[18];
  float* out = (float*)d_out;
  unsigned short* wsW = (unsigned short*)d_ws;

  unsigned short* h0a = (unsigned short*)((char*)d_ws + H0A_OFF);
  unsigned short* h0b = (unsigned short*)((char*)d_ws + H0B_OFF);
  unsigned short* h1a = (unsigned short*)((char*)d_ws + H1A_OFF);
  unsigned short* h1b = (unsigned short*)((char*)d_ws + H1B_OFF);
  unsigned short* gxg = (unsigned short*)((char*)d_ws + GX_OFF);
  float* c0g  = (float*)((char*)d_ws + C0_OFF);
  float* c1g  = (float*)((char*)d_ws + C1_OFF);
  float* posA = (float*)((char*)d_ws + POSA_OFF);
  float* posB = (float*)((char*)d_ws + POSB_OFF);

  hipLaunchKernelGGL(repack, dim3(392), dim3(256), 0, stream,
                     Whh0, Wih1, Whh1, Wp1, wsW);

  hipLaunchKernelGGL(k_init, dim3(256), dim3(512), 0, stream,
                     enc, pos0, ctx, Wh, bh, Wc, bc, Wih0, bih0, bhh0,
                     h0a, h1a, gxg, c0g, c1g, posA);

  unsigned short* h1prev = h1a;
  for (int t = 0; t < NSTEP; t++){
    unsigned short* h0r = (t & 1) ? h0b : h0a;
    unsigned short* h0w = (t & 1) ? h0a : h0b;
    unsigned short* h1r = (t & 1) ? h1b : h1a;
    unsigned short* h1w = (t & 1) ? h1a : h1b;
    float* posRead  = (t == 0) ? posA : ((t & 1) ? posA : posB); // pos_{t-1}
    float* posWrite = (t & 1) ? posB : posA;                     // pos_t

    hipLaunchKernelGGL(k_layer0, dim3(256), dim3(512), 0, stream,
                       wsW, gxg, h0r, h0w, h1prev, c0g,
                       posRead, posWrite, Wih0, bp1, Wp2, bp2, out, t);
    hipLaunchKernelGGL(k_layer1, dim3(256), dim3(512), 0, stream,
                       wsW, h0w, h1r, h1w, c1g, bih1, bhh1);
    h1prev = h1w;
  }
  hipLaunchKernelGGL(k_head, dim3(32), dim3(256), 0, stream,
                     wsW, h1prev, posA, bp1, Wp2, bp2, out, NSTEP-1);
}